// Round 5
// baseline (239.827 us; speedup 1.0000x reference)
//
#include <hip/hip_runtime.h>
#include <math.h>

#define HEADS 8
#define DIM 16
#define NPB 32   // nodes per block = 256 threads / 8 lanes-per-node

static __device__ __forceinline__ unsigned short f2bf(float f) {
  unsigned u = __float_as_uint(f);
  u += 0x7FFFu + ((u >> 16) & 1u);   // round-to-nearest-even
  return (unsigned short)(u >> 16);
}
static __device__ __forceinline__ float bflo(unsigned u) { return __uint_as_float(u << 16); }
static __device__ __forceinline__ float bfhi(unsigned u) { return __uint_as_float(u & 0xFFFF0000u); }

// ---- Pack k,v (fp32, (N,D,H)) into interleaved bf16 rows in workspace:
// kv[i] = 256 bf16 = [k row: flat d*8+h, 128][v row, 128]  (512 B per node)
__global__ __launch_bounds__(256) void conv_kernel(
    const float* __restrict__ k, const float* __restrict__ v,
    unsigned short* __restrict__ kv, int N) {
  int j = blockIdx.x * blockDim.x + threadIdx.x;
  if (j >= N * 32) return;
  int i = j >> 5, c = j & 31;                      // 32 chunks of 8 elems per kv row
  const float* src = (c < 16 ? k : v) + (size_t)i * 128 + (c & 15) * 8;
  float4 f0 = ((const float4*)src)[0];
  float4 f1 = ((const float4*)src)[1];
  uint4 r;
  r.x = (unsigned)f2bf(f0.x) | ((unsigned)f2bf(f0.y) << 16);
  r.y = (unsigned)f2bf(f0.z) | ((unsigned)f2bf(f0.w) << 16);
  r.z = (unsigned)f2bf(f1.x) | ((unsigned)f2bf(f1.y) << 16);
  r.w = (unsigned)f2bf(f1.z) | ((unsigned)f2bf(f1.w) << 16);
  *(uint4*)(kv + (size_t)i * 256 + c * 8) = r;
}

// ---- Main kernel, bf16 gather path.
// Lane l of an 8-lane node-group loads uint4s at kv-row chunk {l, 8+l, 16+l, 24+l}:
// k[d=l][h=0..7], k[d=8+l][..], v[d=l][..], v[d=8+l][..]. Butterfly over the 8
// lanes sums the dot over d; p[h] then multiplies the lane's own v elements.
__global__ __launch_bounds__(256) void spmha_bf16_kernel(
    const float* __restrict__ q, const unsigned short* __restrict__ kv,
    const int* __restrict__ row, const int* __restrict__ col,
    float* __restrict__ out, int N, int E) {
  __shared__ int rp[NPB + 1];
  int node0 = blockIdx.x * NPB;
  if (threadIdx.x <= NPB) {
    int target = node0 + threadIdx.x;
    int lo = 0, hi = E;
    while (lo < hi) {
      int mid = (lo + hi) >> 1;
      if (row[mid] < target) lo = mid + 1; else hi = mid;
    }
    rp[threadIdx.x] = lo;
  }
  __syncthreads();

  int il = threadIdx.x >> 3;
  int i  = node0 + il;
  int l  = threadIdx.x & 7;
  bool alive = (i < N);
  int s = alive ? rp[il] : 0;
  int e = alive ? rp[il + 1] : 0;

  // q for this lane's two d-values, all 8 heads (fp32 keeps logit precision).
  float qv0[8], qv1[8];
  if (alive) {
    const float4* qp = (const float4*)(q + (size_t)i * 128);
    *(float4*)&qv0[0] = qp[2 * l];
    *(float4*)&qv0[4] = qp[2 * l + 1];
    *(float4*)&qv1[0] = qp[16 + 2 * l];
    *(float4*)&qv1[4] = qp[16 + 2 * l + 1];
  }

  float o0[8], o1[8], m[8], den[8];
#pragma unroll
  for (int h = 0; h < 8; ++h) { o0[h] = 0.f; o1[h] = 0.f; m[h] = -INFINITY; den[h] = 0.f; }

  auto cvt8 = [](const uint4& A, float* f) {
    f[0] = bflo(A.x); f[1] = bfhi(A.x); f[2] = bflo(A.y); f[3] = bfhi(A.y);
    f[4] = bflo(A.z); f[5] = bfhi(A.z); f[6] = bflo(A.w); f[7] = bfhi(A.w);
  };

  auto do_edge = [&](const uint4& A, const uint4& B, const uint4& C, const uint4& D) {
    float kf0[8], kf1[8], vf0[8], vf1[8];
    cvt8(A, kf0); cvt8(B, kf1); cvt8(C, vf0); cvt8(D, vf1);
    float part[8];
#pragma unroll
    for (int h = 0; h < 8; ++h) part[h] = fmaf(qv0[h], kf0[h], qv1[h] * kf1[h]);
#pragma unroll
    for (int h = 0; h < 8; ++h) part[h] += __shfl_xor(part[h], 1);
#pragma unroll
    for (int h = 0; h < 8; ++h) part[h] += __shfl_xor(part[h], 2);
#pragma unroll
    for (int h = 0; h < 8; ++h) part[h] += __shfl_xor(part[h], 4);
#pragma unroll
    for (int h = 0; h < 8; ++h) {
      float mn = fmaxf(m[h], part[h]);
      float sc = __expf(m[h] - mn);      // first edge: exp(-inf) = 0
      float p  = __expf(part[h] - mn);
      den[h] = fmaf(den[h], sc, p);
      m[h] = mn;
      o0[h] = fmaf(o0[h], sc, p * vf0[h]);
      o1[h] = fmaf(o1[h], sc, p * vf1[h]);
    }
  };

  int eidx = s;
  for (; eidx + 2 <= e; eidx += 2) {
    int c0 = col[eidx];
    int c1 = col[eidx + 1];
    const uint4* b0 = (const uint4*)(kv + (size_t)c0 * 256);
    const uint4* b1 = (const uint4*)(kv + (size_t)c1 * 256);
    uint4 A0 = b0[l], B0 = b0[8 + l], C0 = b0[16 + l], D0 = b0[24 + l];
    uint4 A1 = b1[l], B1 = b1[8 + l], C1 = b1[16 + l], D1 = b1[24 + l];
    do_edge(A0, B0, C0, D0);
    do_edge(A1, B1, C1, D1);
  }
  if (eidx < e) {
    int c0 = col[eidx];
    const uint4* b0 = (const uint4*)(kv + (size_t)c0 * 256);
    do_edge(b0[l], b0[8 + l], b0[16 + l], b0[24 + l]);
  }

  if (alive) {
    float inv[8];
#pragma unroll
    for (int h = 0; h < 8; ++h) inv[h] = (e > s) ? 1.f / den[h] : 0.f;
    float4* op = (float4*)(out + (size_t)i * 128);
    float4 r;
    r.x = o0[0] * inv[0]; r.y = o0[1] * inv[1]; r.z = o0[2] * inv[2]; r.w = o0[3] * inv[3];
    op[2 * l] = r;
    r.x = o0[4] * inv[4]; r.y = o0[5] * inv[5]; r.z = o0[6] * inv[6]; r.w = o0[7] * inv[7];
    op[2 * l + 1] = r;
    r.x = o1[0] * inv[0]; r.y = o1[1] * inv[1]; r.z = o1[2] * inv[2]; r.w = o1[3] * inv[3];
    op[16 + 2 * l] = r;
    r.x = o1[4] * inv[4]; r.y = o1[5] * inv[5]; r.z = o1[6] * inv[6]; r.w = o1[7] * inv[7];
    op[16 + 2 * l + 1] = r;
  }
}

// ---- Fallback: round-3 fp32 kernel (used only if ws_size is too small).
__global__ __launch_bounds__(256) void spmha_f32_kernel(
    const float* __restrict__ q, const float* __restrict__ k, const float* __restrict__ v,
    const int* __restrict__ row, const int* __restrict__ col,
    float* __restrict__ out, int N, int E) {
  __shared__ int rp[NPB + 1];
  int node0 = blockIdx.x * NPB;
  if (threadIdx.x <= NPB) {
    int target = node0 + threadIdx.x;
    int lo = 0, hi = E;
    while (lo < hi) {
      int mid = (lo + hi) >> 1;
      if (row[mid] < target) lo = mid + 1; else hi = mid;
    }
    rp[threadIdx.x] = lo;
  }
  __syncthreads();

  int il = threadIdx.x >> 3;
  int i  = node0 + il;
  int l  = threadIdx.x & 7;
  bool alive = (i < N);
  int s = alive ? rp[il] : 0;
  int e = alive ? rp[il + 1] : 0;

  float qv[16];
  if (alive) {
    const float4* qb = (const float4*)(q + (size_t)i * 128);
#pragma unroll
    for (int r = 0; r < 4; ++r) *(float4*)&qv[4 * r] = qb[8 * r + l];
  }
  float o[16];
#pragma unroll
  for (int x = 0; x < 16; ++x) o[x] = 0.f;
  float m[4], den[4];
#pragma unroll
  for (int j = 0; j < 4; ++j) { m[j] = -INFINITY; den[j] = 0.f; }

  auto do_edge = [&](const float* kk, const float* vv) {
    float part[4];
#pragma unroll
    for (int j = 0; j < 4; ++j) part[j] = 0.f;
#pragma unroll
    for (int r = 0; r < 4; ++r)
#pragma unroll
      for (int j = 0; j < 4; ++j)
        part[j] = fmaf(qv[4 * r + j], kk[4 * r + j], part[j]);
#pragma unroll
    for (int j = 0; j < 4; ++j) {
      part[j] += __shfl_xor(part[j], 2);
      part[j] += __shfl_xor(part[j], 4);
    }
#pragma unroll
    for (int j = 0; j < 4; ++j) {
      float mn = fmaxf(m[j], part[j]);
      float sc = __expf(m[j] - mn);
      float p  = __expf(part[j] - mn);
      den[j] = fmaf(den[j], sc, p);
      m[j] = mn;
#pragma unroll
      for (int r = 0; r < 4; ++r)
        o[4 * r + j] = fmaf(o[4 * r + j], sc, p * vv[4 * r + j]);
    }
  };

  int eidx = s;
  for (; eidx < e; ++eidx) {
    int c0 = col[eidx];
    const float4* kb0 = (const float4*)(k + (size_t)c0 * 128);
    const float4* vb0 = (const float4*)(v + (size_t)c0 * 128);
    float kk0[16], vv0[16];
#pragma unroll
    for (int r = 0; r < 4; ++r) {
      *(float4*)&kk0[4 * r] = kb0[8 * r + l];
      *(float4*)&vv0[4 * r] = vb0[8 * r + l];
    }
    do_edge(kk0, vv0);
  }

  if (alive) {
    float inv[4];
#pragma unroll
    for (int j = 0; j < 4; ++j) inv[j] = (e > s) ? 1.f / den[j] : 0.f;
    float4* ob = (float4*)(out + (size_t)i * 128);
#pragma unroll
    for (int r = 0; r < 4; ++r) {
      float4 res;
      res.x = o[4 * r + 0] * inv[0];
      res.y = o[4 * r + 1] * inv[1];
      res.z = o[4 * r + 2] * inv[2];
      res.w = o[4 * r + 3] * inv[3];
      ob[8 * r + l] = res;
    }
  }
}

extern "C" void kernel_launch(void* const* d_in, const int* in_sizes, int n_in,
                              void* d_out, int out_size, void* d_ws, size_t ws_size,
                              hipStream_t stream) {
  const float* q   = (const float*)d_in[0];
  const float* k   = (const float*)d_in[1];
  const float* v   = (const float*)d_in[2];
  const int*   row = (const int*)d_in[3];
  const int*   col = (const int*)d_in[4];
  float* out = (float*)d_out;

  int N = in_sizes[0] / (DIM * HEADS);
  int E = in_sizes[3];

  size_t kv_bytes = (size_t)N * 512;   // 256 bf16 per node
  int total = N * HEADS;
  int grid = (total + 255) / 256;

  if (ws_size >= kv_bytes) {
    unsigned short* kv = (unsigned short*)d_ws;
    int cgrid = (N * 32 + 255) / 256;
    conv_kernel<<<cgrid, 256, 0, stream>>>(k, v, kv, N);
    spmha_bf16_kernel<<<grid, 256, 0, stream>>>(q, kv, row, col, out, N, E);
  } else {
    spmha_f32_kernel<<<grid, 256, 0, stream>>>(q, k, v, row, col, out, N, E);
  }
}

// Round 6
// 218.634 us; speedup vs baseline: 1.0969x; 1.0969x over previous
//
#include <hip/hip_runtime.h>
#include <math.h>

#define HEADS 8
#define DIM 16
#define NPB 16   // nodes per block: 256 threads = 32 groups of 8 lanes = 16 nodes x 2 slices

static __device__ __forceinline__ unsigned short f2bf(float f) {
  unsigned u = __float_as_uint(f);
  u += 0x7FFFu + ((u >> 16) & 1u);   // round-to-nearest-even
  return (unsigned short)(u >> 16);
}
static __device__ __forceinline__ float bflo(unsigned u) { return __uint_as_float(u << 16); }
static __device__ __forceinline__ float bfhi(unsigned u) { return __uint_as_float(u & 0xFFFF0000u); }

// ---- Pack k,v (fp32, (N,D,H)) into interleaved bf16 rows in workspace:
// kv[i] = 256 bf16 = [k row: flat d*8+h, 128][v row, 128]  (512 B per node)
__global__ __launch_bounds__(256) void conv_kernel(
    const float* __restrict__ k, const float* __restrict__ v,
    unsigned short* __restrict__ kv, int N) {
  int j = blockIdx.x * blockDim.x + threadIdx.x;
  if (j >= N * 32) return;
  int i = j >> 5, c = j & 31;
  const float* src = (c < 16 ? k : v) + (size_t)i * 128 + (c & 15) * 8;
  float4 f0 = ((const float4*)src)[0];
  float4 f1 = ((const float4*)src)[1];
  uint4 r;
  r.x = (unsigned)f2bf(f0.x) | ((unsigned)f2bf(f0.y) << 16);
  r.y = (unsigned)f2bf(f0.z) | ((unsigned)f2bf(f0.w) << 16);
  r.z = (unsigned)f2bf(f1.x) | ((unsigned)f2bf(f1.y) << 16);
  r.w = (unsigned)f2bf(f1.z) | ((unsigned)f2bf(f1.w) << 16);
  *(uint4*)(kv + (size_t)i * 256 + c * 8) = r;
}

// ---- Main kernel: 2-way edge-sliced flash attention per node.
// Group g (8 lanes): node = g>>1, slice = g&1; slice processes edges s+slice,
// s+slice+2, ... Partial online-softmax states merged across slice pairs via
// __shfl_xor(...,8) (groups 2k and 2k+1 occupy lanes l and l^8 of one wave).
__global__ __launch_bounds__(256) void spmha_bf16_kernel(
    const float* __restrict__ q, const unsigned short* __restrict__ kv,
    const int* __restrict__ row, const int* __restrict__ col,
    float* __restrict__ out, int N, int E) {
  __shared__ int rp[NPB + 1];
  int node0 = blockIdx.x * NPB;
  if (threadIdx.x <= NPB) {
    int target = node0 + threadIdx.x;
    int lo = 0, hi = E;
    while (lo < hi) {
      int mid = (lo + hi) >> 1;
      if (row[mid] < target) lo = mid + 1; else hi = mid;
    }
    rp[threadIdx.x] = lo;
  }
  __syncthreads();

  int g  = threadIdx.x >> 3;   // group 0..31
  int il = g >> 1;             // node within block
  int sl = g & 1;              // slice
  int i  = node0 + il;
  int l  = threadIdx.x & 7;    // lane within group
  bool alive = (i < N);
  int s = alive ? rp[il] : 0;
  int e = alive ? rp[il + 1] : 0;

  // q for this lane's two d-values (d=l and d=8+l), all 8 heads, fp32.
  float qv0[8], qv1[8];
  if (alive) {
    const float4* qp = (const float4*)(q + (size_t)i * 128);
    *(float4*)&qv0[0] = qp[2 * l];
    *(float4*)&qv0[4] = qp[2 * l + 1];
    *(float4*)&qv1[0] = qp[16 + 2 * l];
    *(float4*)&qv1[4] = qp[16 + 2 * l + 1];
  }

  float o0[8], o1[8], m[8], den[8];
#pragma unroll
  for (int h = 0; h < 8; ++h) { o0[h] = 0.f; o1[h] = 0.f; m[h] = -INFINITY; den[h] = 0.f; }

  auto cvt8 = [](const uint4& A, float* f) {
    f[0] = bflo(A.x); f[1] = bfhi(A.x); f[2] = bflo(A.y); f[3] = bfhi(A.y);
    f[4] = bflo(A.z); f[5] = bfhi(A.z); f[6] = bflo(A.w); f[7] = bfhi(A.w);
  };

  auto do_edge = [&](const uint4& A, const uint4& B, const uint4& C, const uint4& D) {
    float kf0[8], kf1[8], vf0[8], vf1[8];
    cvt8(A, kf0); cvt8(B, kf1); cvt8(C, vf0); cvt8(D, vf1);
    float part[8];
#pragma unroll
    for (int h = 0; h < 8; ++h) part[h] = fmaf(qv0[h], kf0[h], qv1[h] * kf1[h]);
#pragma unroll
    for (int h = 0; h < 8; ++h) part[h] += __shfl_xor(part[h], 1);
#pragma unroll
    for (int h = 0; h < 8; ++h) part[h] += __shfl_xor(part[h], 2);
#pragma unroll
    for (int h = 0; h < 8; ++h) part[h] += __shfl_xor(part[h], 4);
#pragma unroll
    for (int h = 0; h < 8; ++h) {
      float mn = fmaxf(m[h], part[h]);
      float sc = __expf(m[h] - mn);      // first edge: exp(-inf) = 0
      float p  = __expf(part[h] - mn);
      den[h] = fmaf(den[h], sc, p);
      m[h] = mn;
      o0[h] = fmaf(o0[h], sc, p * vf0[h]);
      o1[h] = fmaf(o1[h], sc, p * vf1[h]);
    }
  };

  // Slice walks edges s+sl, s+sl+2, ... ; 2x unrolled (two gathers in flight).
  int eidx = s + sl;
  for (; eidx + 2 < e; eidx += 4) {
    int c0 = col[eidx];
    int c1 = col[eidx + 2];
    const uint4* b0 = (const uint4*)(kv + (size_t)c0 * 256);
    const uint4* b1 = (const uint4*)(kv + (size_t)c1 * 256);
    uint4 A0 = b0[l], B0 = b0[8 + l], C0 = b0[16 + l], D0 = b0[24 + l];
    uint4 A1 = b1[l], B1 = b1[8 + l], C1 = b1[16 + l], D1 = b1[24 + l];
    do_edge(A0, B0, C0, D0);
    do_edge(A1, B1, C1, D1);
  }
  if (eidx < e) {
    int c0 = col[eidx];
    const uint4* b0 = (const uint4*)(kv + (size_t)c0 * 256);
    do_edge(b0[l], b0[8 + l], b0[16 + l], b0[24 + l]);
  }

  // Merge the two slices' partial flash states: lane l <-> lane l^8.
#pragma unroll
  for (int h = 0; h < 8; ++h) {
    float m_o   = __shfl_xor(m[h], 8);
    float den_o = __shfl_xor(den[h], 8);
    float o0_o  = __shfl_xor(o0[h], 8);
    float o1_o  = __shfl_xor(o1[h], 8);
    float mn = fmaxf(m[h], m_o);
    float a  = __expf(m[h] - mn);   // NaN only if deg==0 (both -inf) -> zero-write path
    float b  = __expf(m_o - mn);
    den[h] = den[h] * a + den_o * b;
    o0[h]  = o0[h] * a + o0_o * b;
    o1[h]  = o1[h] * a + o1_o * b;
  }

  if (alive && sl == 0) {
    float4* op = (float4*)(out + (size_t)i * 128);
    if (e > s) {
      float inv[8];
#pragma unroll
      for (int h = 0; h < 8; ++h) inv[h] = 1.f / den[h];
      float4 r;
      r.x = o0[0] * inv[0]; r.y = o0[1] * inv[1]; r.z = o0[2] * inv[2]; r.w = o0[3] * inv[3];
      op[2 * l] = r;
      r.x = o0[4] * inv[4]; r.y = o0[5] * inv[5]; r.z = o0[6] * inv[6]; r.w = o0[7] * inv[7];
      op[2 * l + 1] = r;
      r.x = o1[0] * inv[0]; r.y = o1[1] * inv[1]; r.z = o1[2] * inv[2]; r.w = o1[3] * inv[3];
      op[16 + 2 * l] = r;
      r.x = o1[4] * inv[4]; r.y = o1[5] * inv[5]; r.z = o1[6] * inv[6]; r.w = o1[7] * inv[7];
      op[16 + 2 * l + 1] = r;
    } else {
      float4 z = make_float4(0.f, 0.f, 0.f, 0.f);
      op[2 * l] = z; op[2 * l + 1] = z; op[16 + 2 * l] = z; op[16 + 2 * l + 1] = z;
    }
  }
}

// ---- Fallback: fp32 kernel (used only if ws_size is too small).
__global__ __launch_bounds__(256) void spmha_f32_kernel(
    const float* __restrict__ q, const float* __restrict__ k, const float* __restrict__ v,
    const int* __restrict__ row, const int* __restrict__ col,
    float* __restrict__ out, int N, int E) {
  __shared__ int rp[33];
  int node0 = blockIdx.x * 32;
  if (threadIdx.x <= 32) {
    int target = node0 + threadIdx.x;
    int lo = 0, hi = E;
    while (lo < hi) {
      int mid = (lo + hi) >> 1;
      if (row[mid] < target) lo = mid + 1; else hi = mid;
    }
    rp[threadIdx.x] = lo;
  }
  __syncthreads();

  int il = threadIdx.x >> 3;
  int i  = node0 + il;
  int l  = threadIdx.x & 7;
  bool alive = (i < N);
  int s = alive ? rp[il] : 0;
  int e = alive ? rp[il + 1] : 0;

  float qv[16];
  if (alive) {
    const float4* qb = (const float4*)(q + (size_t)i * 128);
#pragma unroll
    for (int r = 0; r < 4; ++r) *(float4*)&qv[4 * r] = qb[8 * r + l];
  }
  float o[16];
#pragma unroll
  for (int x = 0; x < 16; ++x) o[x] = 0.f;
  float m[4], den[4];
#pragma unroll
  for (int j = 0; j < 4; ++j) { m[j] = -INFINITY; den[j] = 0.f; }

  auto do_edge = [&](const float* kk, const float* vv) {
    float part[4];
#pragma unroll
    for (int j = 0; j < 4; ++j) part[j] = 0.f;
#pragma unroll
    for (int r = 0; r < 4; ++r)
#pragma unroll
      for (int j = 0; j < 4; ++j)
        part[j] = fmaf(qv[4 * r + j], kk[4 * r + j], part[j]);
#pragma unroll
    for (int j = 0; j < 4; ++j) {
      part[j] += __shfl_xor(part[j], 2);
      part[j] += __shfl_xor(part[j], 4);
    }
#pragma unroll
    for (int j = 0; j < 4; ++j) {
      float mn = fmaxf(m[j], part[j]);
      float sc = __expf(m[j] - mn);
      float p  = __expf(part[j] - mn);
      den[j] = fmaf(den[j], sc, p);
      m[j] = mn;
#pragma unroll
      for (int r = 0; r < 4; ++r)
        o[4 * r + j] = fmaf(o[4 * r + j], sc, p * vv[4 * r + j]);
    }
  };

  for (int eidx = s; eidx < e; ++eidx) {
    int c0 = col[eidx];
    const float4* kb0 = (const float4*)(k + (size_t)c0 * 128);
    const float4* vb0 = (const float4*)(v + (size_t)c0 * 128);
    float kk0[16], vv0[16];
#pragma unroll
    for (int r = 0; r < 4; ++r) {
      *(float4*)&kk0[4 * r] = kb0[8 * r + l];
      *(float4*)&vv0[4 * r] = vb0[8 * r + l];
    }
    do_edge(kk0, vv0);
  }

  if (alive) {
    float inv[4];
#pragma unroll
    for (int j = 0; j < 4; ++j) inv[j] = (e > s) ? 1.f / den[j] : 0.f;
    float4* ob = (float4*)(out + (size_t)i * 128);
#pragma unroll
    for (int r = 0; r < 4; ++r) {
      float4 res;
      res.x = o[4 * r + 0] * inv[0];
      res.y = o[4 * r + 1] * inv[1];
      res.z = o[4 * r + 2] * inv[2];
      res.w = o[4 * r + 3] * inv[3];
      ob[8 * r + l] = res;
    }
  }
}

extern "C" void kernel_launch(void* const* d_in, const int* in_sizes, int n_in,
                              void* d_out, int out_size, void* d_ws, size_t ws_size,
                              hipStream_t stream) {
  const float* q   = (const float*)d_in[0];
  const float* k   = (const float*)d_in[1];
  const float* v   = (const float*)d_in[2];
  const int*   row = (const int*)d_in[3];
  const int*   col = (const int*)d_in[4];
  float* out = (float*)d_out;

  int N = in_sizes[0] / (DIM * HEADS);
  int E = in_sizes[3];

  size_t kv_bytes = (size_t)N * 512;

  if (ws_size >= kv_bytes) {
    unsigned short* kv = (unsigned short*)d_ws;
    int cgrid = (N * 32 + 255) / 256;
    conv_kernel<<<cgrid, 256, 0, stream>>>(k, v, kv, N);
    int grid = (N + NPB - 1) / NPB;   // 16 nodes per block
    spmha_bf16_kernel<<<grid, 256, 0, stream>>>(q, kv, row, col, out, N, E);
  } else {
    int total = N * HEADS;
    int grid = (total + 255) / 256;
    spmha_f32_kernel<<<grid, 256, 0, stream>>>(q, k, v, row, col, out, N, E);
  }
}